// Round 2
// baseline (261.154 us; speedup 1.0000x reference)
//
#include <hip/hip_runtime.h>
#include <math.h>

using bf16x8 = __attribute__((ext_vector_type(8))) short;
using f32x4  = __attribute__((ext_vector_type(4))) float;
using u32x2  = __attribute__((ext_vector_type(2))) unsigned int;

namespace {
constexpr int kB  = 4;
constexpr int kLQ = 1024;
constexpr int kLK = 2048;
constexpr int kH  = 1024;
constexpr int kHD = 64;
}

__device__ __forceinline__ unsigned short f2bf(float x) {
  union { float f; unsigned int u; } v; v.f = x;
  unsigned int r = v.u + 0x7fffu + ((v.u >> 16) & 1u);   // RNE
  return (unsigned short)(r >> 16);
}

// async global->LDS 16B copy
typedef const __attribute__((address_space(1))) unsigned int guint_t;
typedef __attribute__((address_space(3))) unsigned int luint_t;
__device__ __forceinline__ void g2l16(const void* g, void* l) {
  __builtin_amdgcn_global_load_lds(
      (guint_t*)g,
      (luint_t*)(unsigned int)(unsigned long long)l,
      16, 0, 0);
}

// --------- fused prep: fp32->bf16 casts (q,k,v) + 4 weight transposes --------
__global__ __launch_bounds__(256) void prep_kernel(
    const float* __restrict__ q, const float* __restrict__ k,
    const float* __restrict__ v, const float* __restrict__ Wq,
    const float* __restrict__ Wk, const float* __restrict__ Wv,
    const float* __restrict__ Wo, unsigned short* __restrict__ qo,
    unsigned short* __restrict__ ko, unsigned short* __restrict__ vo,
    unsigned short* __restrict__ WqT, unsigned short* __restrict__ WkT,
    unsigned short* __restrict__ WvT, unsigned short* __restrict__ WoT)
{
  __shared__ float tile[64][65];
  const int t = threadIdx.x;
  if (blockIdx.x < 5632) {
    int c = blockIdx.x * 256 + t;
    const float* src; unsigned short* dst;
    if (c < 393216)      { src = q; dst = qo; }
    else if (c < 917504) { src = k; dst = ko; c -= 393216; }
    else                 { src = v; dst = vo; c -= 917504; }
    const int i = c * 8;
    const float4 a = *(const float4*)(src + i);
    const float4 b = *(const float4*)(src + i + 4);
    uint4 o;
    o.x = (unsigned int)f2bf(a.x) | ((unsigned int)f2bf(a.y) << 16);
    o.y = (unsigned int)f2bf(a.z) | ((unsigned int)f2bf(a.w) << 16);
    o.z = (unsigned int)f2bf(b.x) | ((unsigned int)f2bf(b.y) << 16);
    o.w = (unsigned int)f2bf(b.z) | ((unsigned int)f2bf(b.w) << 16);
    *(uint4*)(dst + i) = o;
    return;
  }
  int id = blockIdx.x - 5632;
  const float* W; unsigned short* Wt; int Kd;
  if (id < 192)      { W = Wq; Wt = WqT; Kd = 768; }
  else if (id < 320) { W = Wk; Wt = WkT; Kd = 512;  id -= 192; }
  else if (id < 448) { W = Wv; Wt = WvT; Kd = 512;  id -= 320; }
  else               { W = Wo; Wt = WoT; Kd = 1024; id -= 448; }
  const int Nd = 1024;
  const int n0 = (id & 15) * 64;
  const int k0 = (id >> 4) * 64;
  const int rr = t >> 4;
  const int c4 = t & 15;
#pragma unroll
  for (int i = 0; i < 4; ++i) {
    const int row = i * 16 + rr;
    const float4 vv = *(const float4*)(W + (size_t)(k0 + row) * Nd + n0 + c4 * 4);
    tile[row][c4*4+0] = vv.x; tile[row][c4*4+1] = vv.y;
    tile[row][c4*4+2] = vv.z; tile[row][c4*4+3] = vv.w;
  }
  __syncthreads();
#pragma unroll
  for (int i = 0; i < 4; ++i) {
    const int n = i * 16 + rr;
    ushort4 o;
    o.x = f2bf(tile[c4*4+0][n]); o.y = f2bf(tile[c4*4+1][n]);
    o.z = f2bf(tile[c4*4+2][n]); o.w = f2bf(tile[c4*4+3][n]);
    *(ushort4*)(Wt + (size_t)(n0 + n) * Kd + k0 + c4 * 4) = o;
  }
}

// ---- GEMM body: 128x256 tile, 8 waves, BK=32, double-buffered g2l pipeline --
// One 128-row A panel feeds TWO 128-col B panels (cols c0 and c0+128): A is
// staged once per K-step for 2x the MFMA per barrier. Wave w: panel p=w>>2,
// wm=(w>>1)&1, wn=w&1 -> 64x64 subtile. Per-thread g2l: 3 (was 4 at 128x128).
// mode 0: fp32 out. mode 1: bf16 out, (acc+bias)*scale. mode 2: bf16 out V-T.
__device__ __forceinline__ void gemm_body2(
    const unsigned short* __restrict__ pA,   // A + r0*K
    const unsigned short* __restrict__ pB1,  // Bt + c0*K       (128 rows)
    const unsigned short* __restrict__ pB2,  // Bt + (c0+128)*K (128 rows)
    const float* __restrict__ bias, void* __restrict__ Cout,
    int c0, int r0, int N, int K, int mode, float scale, char* lds)
{
  const int t    = threadIdx.x;
  const int lane = t & 63;
  const int w    = t >> 6;
  const int l15  = lane & 15;
  const int lq8  = (lane >> 4) * 8;
  const int lq4  = (lane >> 4) * 4;
  const int p    = w >> 2;
  const int wm   = (w >> 1) & 1;
  const int wn   = w & 1;

  f32x4 acc[4][4] = {};

  // prologue: prefetch k0=0 into buffer 0 (A: g 0..7, B1: 8..15, B2: 16..23)
#pragma unroll
  for (int i = 0; i < 3; ++i) {
    const int g = w * 3 + i;
    const unsigned short* src = (g < 8) ? pA : (g < 16 ? pB1 : pB2);
    const int sub = g & 7;
    g2l16(src + (size_t)(sub * 16 + l15) * K + lq8, lds + g * 1024 + lane * 16);
  }

  const int bbase = 8192 + p * 8192;
  int pb = 0;
  for (int k0 = 0; k0 < K; k0 += 32, pb ^= 1) {
    __syncthreads();   // cur buffer's g2l drained (issued one compute-phase ago)
    char* buf = lds + pb * 24576;
    if (k0 + 32 < K) {
      char* nbuf = lds + (pb ^ 1) * 24576;
#pragma unroll
      for (int i = 0; i < 3; ++i) {
        const int g = w * 3 + i;
        const unsigned short* src = (g < 8) ? pA : (g < 16 ? pB1 : pB2);
        const int sub = g & 7;
        g2l16(src + (size_t)(sub * 16 + l15) * K + k0 + 32 + lq8, nbuf + g * 1024 + lane * 16);
      }
    }
    bf16x8 af[4], bfr[4];
#pragma unroll
    for (int i = 0; i < 4; ++i) af[i]  = *(const bf16x8*)(buf + (wm*4 + i) * 1024 + lane * 16);
#pragma unroll
    for (int j = 0; j < 4; ++j) bfr[j] = *(const bf16x8*)(buf + bbase + (wn*4 + j) * 1024 + lane * 16);
#pragma unroll
    for (int i = 0; i < 4; ++i)
#pragma unroll
      for (int j = 0; j < 4; ++j)
        acc[i][j] = __builtin_amdgcn_mfma_f32_16x16x32_bf16(af[i], bfr[j], acc[i][j], 0, 0, 0);
  }

#pragma unroll
  for (int j = 0; j < 4; ++j) {
    const int col = c0 + p * 128 + wn * 64 + j * 16 + l15;
    const float bcol = bias[col];
#pragma unroll
    for (int i = 0; i < 4; ++i) {
      const int row = r0 + wm * 64 + i * 16 + lq4;
      if (mode == 0) {
        float* out = (float*)Cout;
#pragma unroll
        for (int r = 0; r < 4; ++r) out[(size_t)(row + r) * N + col] = acc[i][j][r] + bcol;
      } else if (mode == 1) {
        unsigned short* out = (unsigned short*)Cout;
#pragma unroll
        for (int r = 0; r < 4; ++r) out[(size_t)(row + r) * N + col] = f2bf((acc[i][j][r] + bcol) * scale);
      } else {
        unsigned short* out = (unsigned short*)Cout;
        const int bb = row >> 11;            // kLK = 2048
        const int lk = row & 2047;
        ushort4 o;
        o.x = f2bf(acc[i][j][0] + bcol); o.y = f2bf(acc[i][j][1] + bcol);
        o.z = f2bf(acc[i][j][2] + bcol); o.w = f2bf(acc[i][j][3] + bcol);
        *(ushort4*)(out + (size_t)(bb * kH + col) * kLK + lk) = o;
      }
    }
  }
}

// fused Q/K/V projections, XCD-swizzled grid of 640 blocks x 512 threads:
// logical 0..127 Q (128x256 tiles) | 128..383 K | 384..639 V.
// Q projection pre-scaled by log2(e)/sqrt(HD) so attn exp2 needs no multiply.
__global__ __launch_bounds__(512, 4) void qkv_gemm_kernel(
    const unsigned short* __restrict__ qA, const unsigned short* __restrict__ WqT,
    const float* __restrict__ bq, unsigned short* __restrict__ Qb,
    const unsigned short* __restrict__ kA, const unsigned short* __restrict__ WkT,
    const float* __restrict__ bk, unsigned short* __restrict__ Kb,
    const unsigned short* __restrict__ vA, const unsigned short* __restrict__ WvT,
    const float* __restrict__ bv, unsigned short* __restrict__ Vtw)
{
  __shared__ __align__(16) char lds[49152];
  const int bid = blockIdx.x;
  const int lg = (bid & 7) * 80 + (bid >> 3);   // XCD swizzle, nwg=640
  if (lg < 128) {
    const int bx = lg & 3, by = lg >> 2;        // 4 x 32
    const int r0 = by * 128, c0 = bx * 256;
    gemm_body2(qA + (size_t)r0 * 768,
               WqT + (size_t)c0 * 768, WqT + (size_t)(c0 + 128) * 768,
               bq, Qb, c0, r0, 1024, 768, 1, 0.18033688011112042f, lds);
  } else if (lg < 384) {
    const int id = lg - 128;
    const int bx = id & 3, by = id >> 2;        // 4 x 64
    const int r0 = by * 128, c0 = bx * 256;
    gemm_body2(kA + (size_t)r0 * 512,
               WkT + (size_t)c0 * 512, WkT + (size_t)(c0 + 128) * 512,
               bk, Kb, c0, r0, 1024, 512, 1, 1.f, lds);
  } else {
    const int id = lg - 384;
    const int bx = id & 3, by = id >> 2;        // 4 x 64
    const int r0 = by * 128, c0 = bx * 256;
    gemm_body2(vA + (size_t)r0 * 512,
               WvT + (size_t)c0 * 512, WvT + (size_t)(c0 + 128) * 512,
               bv, Vtw, c0, r0, 1024, 512, 2, 1.f, lds);
  }
}

// out projection: fp32 out, 128 blocks (4 x 32 tiles of 128x256), XCD-swizzled
__global__ __launch_bounds__(512, 4) void out_gemm_kernel(
    const unsigned short* __restrict__ A, const unsigned short* __restrict__ Bt,
    const float* __restrict__ bias, float* __restrict__ C)
{
  __shared__ __align__(16) char lds[49152];
  const int bid = blockIdx.x;
  const int lg = (bid & 7) * 16 + (bid >> 3);   // XCD swizzle, nwg=128
  const int bx = lg & 3, by = lg >> 2;          // 4 x 32
  const int r0 = by * 128, c0 = bx * 256;
  gemm_body2(A + (size_t)r0 * 1024,
             Bt + (size_t)c0 * 1024, Bt + (size_t)(c0 + 128) * 1024,
             bias, C, c0, r0, 1024, 1024, 0, 1.f, lds);
}

// --------------------- MFMA flash attention (bf16, fp32 acc) -----------------
// Q [B*LQ, H] (pre-scaled by log2e/8), K [B*LK, H], Vt [B*H, LK], O [B*LQ, H].
// 128 q-rows/block, 4 waves x 32 q-rows; kc-tile = 64, double-buffered K/V via
// g2l prefetch pipeline (1 barrier/iter). Grid flat = qb*64 + bh: same-(b,h)
// blocks share an XCD.
// QK^T is computed SWAPPED (mfma(K,Q) = S^T) so each lane holds 4 consecutive
// kc of one q-row -> P packs into 8 ds_write_b64/iter (was 32 ds_write_b16).
// P LDS layout [q][kc] stride 72 bf16 is unchanged, so PV reads are identical.
__global__ __launch_bounds__(256) void attn_mfma_kernel(
    const unsigned short* __restrict__ Q, const unsigned short* __restrict__ K,
    const unsigned short* __restrict__ Vt, unsigned short* __restrict__ O)
{
  // buf p at p*16384: K tile [0,8K) + V tile [8K,16K). P at 32768 (128 x 72 bf16)
  __shared__ __align__(16) char lds[51200];
  constexpr int POFF = 32768;
  const int t    = threadIdx.x;
  const int lane = t & 63;
  const int w    = t >> 6;
  const int l15  = lane & 15;
  const int lg   = lane >> 4;
  const int lq8  = lg * 8;
  const int lq4  = lg * 4;
  const int flat = blockIdx.x;
  const int bh   = flat & 63;
  const int qb   = flat >> 6;
  const int h    = bh & 15;
  const int b    = bh >> 4;
  const int q0   = qb * 128;
  const int hoff = h * kHD;

  bf16x8 qf[2][2];
#pragma unroll
  for (int qi = 0; qi < 2; ++qi)
#pragma unroll
    for (int kh = 0; kh < 2; ++kh)
      qf[qi][kh] = *(const bf16x8*)(Q + (size_t)(b*kLQ + q0 + w*32 + qi*16 + l15) * kH
                                      + hoff + kh*32 + lq8);

  f32x4 acc[2][4] = {};
  float lsum[2] = {0.f, 0.f};

  // P store base: row q = w*32 + qi*16 + l15, cols kcf*16 + lq4 .. +3
  char* const pwr = lds + POFF + (w*32 + l15) * 144 + lq4 * 2;
  // P read base: row q = w*32 + qi*16 + l15, cols kq*32 + lq8 .. +7
  const char* const prd = lds + POFF + (w*32 + l15) * 144 + lq8 * 2;

  // prologue: prefetch tile 0 into buffer 0
#pragma unroll
  for (int i = 0; i < 4; ++i) {
    const int g = w * 4 + i;
    if (g < 8) {
      g2l16(K + (size_t)(b*kLK + (g >> 1)*16 + l15) * kH + hoff + (g & 1)*32 + lq8,
            lds + g * 1024 + lane * 16);
    } else {
      const int gg = g - 8;
      g2l16(Vt + (size_t)(b*kH + hoff + (gg >> 1)*16 + l15) * kLK + (gg & 1)*32 + lq8,
            lds + 8192 + gg * 1024 + lane * 16);
    }
  }

  int pb = 0;
  for (int kt = 0; kt < kLK / 64; ++kt, pb ^= 1) {
    __syncthreads();   // cur buffer ready (g2l issued one compute-phase ago)
    char* buf = lds + pb * 16384;
    if (kt + 1 < kLK / 64) {
      char* nbuf = lds + (pb ^ 1) * 16384;
      const int kc1 = (kt + 1) * 64;
#pragma unroll
      for (int i = 0; i < 4; ++i) {
        const int g = w * 4 + i;
        if (g < 8) {
          g2l16(K + (size_t)(b*kLK + kc1 + (g >> 1)*16 + l15) * kH + hoff + (g & 1)*32 + lq8,
                nbuf + g * 1024 + lane * 16);
        } else {
          const int gg = g - 8;
          g2l16(Vt + (size_t)(b*kH + hoff + (gg >> 1)*16 + l15) * kLK + kc1 + (gg & 1)*32 + lq8,
                nbuf + 8192 + gg * 1024 + lane * 16);
        }
      }
    }

    // S^T = K Q^T : lane holds S[kc = kcf*16+lq4+r][q = w*32+qi*16+l15]
    f32x4 s[2][4];
#pragma unroll
    for (int kcf = 0; kcf < 4; ++kcf) {
      const bf16x8 kf0 = *(const bf16x8*)(buf + (kcf*2 + 0) * 1024 + lane * 16);
      const bf16x8 kf1 = *(const bf16x8*)(buf + (kcf*2 + 1) * 1024 + lane * 16);
#pragma unroll
      for (int qi = 0; qi < 2; ++qi) {
        f32x4 z = {};
        z = __builtin_amdgcn_mfma_f32_16x16x32_bf16(kf0, qf[qi][0], z, 0, 0, 0);
        z = __builtin_amdgcn_mfma_f32_16x16x32_bf16(kf1, qf[qi][1], z, 0, 0, 0);
        s[qi][kcf] = z;
      }
    }

    // P = exp2(s) (Q pre-scaled); pack 4 kc -> one b64 store per (qi,kcf).
    // bf16 by truncation (bias cancels via norm), packed with v_perm.
#pragma unroll
    for (int qi = 0; qi < 2; ++qi)
#pragma unroll
      for (int kcf = 0; kcf < 4; ++kcf) {
        const float p0 = __builtin_amdgcn_exp2f(s[qi][kcf][0]);
        const float p1 = __builtin_amdgcn_exp2f(s[qi][kcf][1]);
        const float p2 = __builtin_amdgcn_exp2f(s[qi][kcf][2]);
        const float p3 = __builtin_amdgcn_exp2f(s[qi][kcf][3]);
        lsum[qi] += (p0 + p1) + (p2 + p3);
        u32x2 pw;
        pw.x = __builtin_amdgcn_perm(__float_as_uint(p1), __float_as_uint(p0), 0x07060302u);
        pw.y = __builtin_amdgcn_perm(__float_as_uint(p3), __float_as_uint(p2), 0x07060302u);
        *(u32x2*)(pwr + qi*2304 + kcf*32) = pw;
      }

    // O += P V (P rows per-wave-private; no barrier needed)
    bf16x8 pf[2][2];
#pragma unroll
    for (int qi = 0; qi < 2; ++qi)
#pragma unroll
      for (int kq = 0; kq < 2; ++kq)
        pf[qi][kq] = *(const bf16x8*)(prd + qi*2304 + kq*64);
#pragma unroll
    for (int vd = 0; vd < 4; ++vd) {
      const bf16x8 vf0 = *(const bf16x8*)(buf + 8192 + (vd*2 + 0) * 1024 + lane * 16);
      const bf16x8 vf1 = *(const bf16x8*)(buf + 8192 + (vd*2 + 1) * 1024 + lane * 16);
#pragma unroll
      for (int qi = 0; qi < 2; ++qi) {
        acc[qi][vd] = __builtin_amdgcn_mfma_f32_16x16x32_bf16(pf[qi][0], vf0, acc[qi][vd], 0, 0, 0);
        acc[qi][vd] = __builtin_amdgcn_mfma_f32_16x16x32_bf16(pf[qi][1], vf1, acc[qi][vd], 0, 0, 0);
      }
    }
  }

  // row sums: lane holds partial for q = l15 over its kc slice; reduce across
  // the 4 lane-groups, then redistribute 1/sum to acc row owners (q = lq4+r).
  float rinv[2][4];
#pragma unroll
  for (int qi = 0; qi < 2; ++qi) {
    float v = lsum[qi];
    v += __shfl_xor(v, 16);
    v += __shfl_xor(v, 32);
    v = 1.f / v;
#pragma unroll
    for (int r = 0; r < 4; ++r) rinv[qi][r] = __shfl(v, lq4 + r);
  }
#pragma unroll
  for (int qi = 0; qi < 2; ++qi)
#pragma unroll
    for (int vd = 0; vd < 4; ++vd)
#pragma unroll
      for (int r = 0; r < 4; ++r)
        O[(size_t)(b*kLQ + q0 + w*32 + qi*16 + lq4 + r) * kH + hoff + vd*16 + l15] =
            f2bf(acc[qi][vd][r] * rinv[qi][r]);
}

extern "C" void kernel_launch(void* const* d_in, const int* in_sizes, int n_in,
                              void* d_out, int out_size, void* d_ws, size_t ws_size,
                              hipStream_t stream) {
  (void)in_sizes; (void)n_in; (void)out_size; (void)ws_size;
  const float* query = (const float*)d_in[0];
  const float* key   = (const float*)d_in[1];
  const float* value = (const float*)d_in[2];
  const float* Wq = (const float*)d_in[3];
  const float* bq = (const float*)d_in[4];
  const float* Wk = (const float*)d_in[5];
  const float* bk = (const float*)d_in[6];
  const float* Wv = (const float*)d_in[7];
  const float* bv = (const float*)d_in[8];
  const float* Wo = (const float*)d_in[9];
  const float* bo = (const float*)d_in[10];
  float* out = (float*)d_out;

  unsigned short* ws  = (unsigned short*)d_ws;
  unsigned short* qA  = ws;                  // 4*1024*768
  unsigned short* kA  = qA  + 3145728;       // 4*2048*512
  unsigned short* vA  = kA  + 4194304;
  unsigned short* WqT = vA  + 4194304;       // 1024*768
  unsigned short* WkT = WqT + 786432;        // 1024*512
  unsigned short* WvT = WkT + 524288;
  unsigned short* WoT = WvT + 524288;        // 1024*1024
  unsigned short* Qb  = WoT + 1048576;       // 4096*1024
  unsigned short* Kb  = Qb  + 4194304;       // 8192*1024
  unsigned short* Vtw = Kb  + 8388608;       // 4096*2048 (transposed V)
  unsigned short* Ab  = Vtw + 8388608;       // 4096*1024

  prep_kernel<<<6336, 256, 0, stream>>>(query, key, value, Wq, Wk, Wv, Wo,
                                        qA, kA, vA, WqT, WkT, WvT, WoT);
  qkv_gemm_kernel<<<640, 512, 0, stream>>>(qA, WqT, bq, Qb,
                                           kA, WkT, bk, Kb,
                                           vA, WvT, bv, Vtw);
  attn_mfma_kernel<<<512, 256, 0, stream>>>(Qb, Kb, Vtw, Ab);
  out_gemm_kernel<<<128, 512, 0, stream>>>(Ab, WoT, bo, out);
}

// Round 3
// 256.313 us; speedup vs baseline: 1.0189x; 1.0189x over previous
//
#include <hip/hip_runtime.h>
#include <math.h>

using bf16x8 = __attribute__((ext_vector_type(8))) short;
using f32x4  = __attribute__((ext_vector_type(4))) float;
using u32x2  = __attribute__((ext_vector_type(2))) unsigned int;

namespace {
constexpr int kB  = 4;
constexpr int kLQ = 1024;
constexpr int kLK = 2048;
constexpr int kH  = 1024;
constexpr int kHD = 64;
}

__device__ __forceinline__ unsigned short f2bf(float x) {
  union { float f; unsigned int u; } v; v.f = x;
  unsigned int r = v.u + 0x7fffu + ((v.u >> 16) & 1u);   // RNE
  return (unsigned short)(r >> 16);
}

// async global->LDS 16B copy
typedef const __attribute__((address_space(1))) unsigned int guint_t;
typedef __attribute__((address_space(3))) unsigned int luint_t;
__device__ __forceinline__ void g2l16(const void* g, void* l) {
  __builtin_amdgcn_global_load_lds(
      (guint_t*)g,
      (luint_t*)(unsigned int)(unsigned long long)l,
      16, 0, 0);
}

// --------- fused prep: fp32->bf16 casts (q,k,v) + 4 weight transposes --------
__global__ __launch_bounds__(256) void prep_kernel(
    const float* __restrict__ q, const float* __restrict__ k,
    const float* __restrict__ v, const float* __restrict__ Wq,
    const float* __restrict__ Wk, const float* __restrict__ Wv,
    const float* __restrict__ Wo, unsigned short* __restrict__ qo,
    unsigned short* __restrict__ ko, unsigned short* __restrict__ vo,
    unsigned short* __restrict__ WqT, unsigned short* __restrict__ WkT,
    unsigned short* __restrict__ WvT, unsigned short* __restrict__ WoT)
{
  __shared__ float tile[64][65];
  const int t = threadIdx.x;
  if (blockIdx.x < 5632) {
    int c = blockIdx.x * 256 + t;
    const float* src; unsigned short* dst;
    if (c < 393216)      { src = q; dst = qo; }
    else if (c < 917504) { src = k; dst = ko; c -= 393216; }
    else                 { src = v; dst = vo; c -= 917504; }
    const int i = c * 8;
    const float4 a = *(const float4*)(src + i);
    const float4 b = *(const float4*)(src + i + 4);
    uint4 o;
    o.x = (unsigned int)f2bf(a.x) | ((unsigned int)f2bf(a.y) << 16);
    o.y = (unsigned int)f2bf(a.z) | ((unsigned int)f2bf(a.w) << 16);
    o.z = (unsigned int)f2bf(b.x) | ((unsigned int)f2bf(b.y) << 16);
    o.w = (unsigned int)f2bf(b.z) | ((unsigned int)f2bf(b.w) << 16);
    *(uint4*)(dst + i) = o;
    return;
  }
  int id = blockIdx.x - 5632;
  const float* W; unsigned short* Wt; int Kd;
  if (id < 192)      { W = Wq; Wt = WqT; Kd = 768; }
  else if (id < 320) { W = Wk; Wt = WkT; Kd = 512;  id -= 192; }
  else if (id < 448) { W = Wv; Wt = WvT; Kd = 512;  id -= 320; }
  else               { W = Wo; Wt = WoT; Kd = 1024; id -= 448; }
  const int Nd = 1024;
  const int n0 = (id & 15) * 64;
  const int k0 = (id >> 4) * 64;
  const int rr = t >> 4;
  const int c4 = t & 15;
#pragma unroll
  for (int i = 0; i < 4; ++i) {
    const int row = i * 16 + rr;
    const float4 vv = *(const float4*)(W + (size_t)(k0 + row) * Nd + n0 + c4 * 4);
    tile[row][c4*4+0] = vv.x; tile[row][c4*4+1] = vv.y;
    tile[row][c4*4+2] = vv.z; tile[row][c4*4+3] = vv.w;
  }
  __syncthreads();
#pragma unroll
  for (int i = 0; i < 4; ++i) {
    const int n = i * 16 + rr;
    ushort4 o;
    o.x = f2bf(tile[c4*4+0][n]); o.y = f2bf(tile[c4*4+1][n]);
    o.z = f2bf(tile[c4*4+2][n]); o.w = f2bf(tile[c4*4+3][n]);
    *(ushort4*)(Wt + (size_t)(n0 + n) * Kd + k0 + c4 * 4) = o;
  }
}

// ---- GEMM body: 128x128 tile, BK=32, double-buffered g2l pipeline -----------
// mode 0: fp32 out. mode 1: bf16 out, (acc+bias)*scale. mode 2: bf16 out V-T.
__device__ __forceinline__ void gemm_body(
    const unsigned short* __restrict__ A, const unsigned short* __restrict__ Bt,
    const float* __restrict__ bias, void* __restrict__ Cout,
    int N, int K, int bx, int by, int mode, float scale, char* lds)
{
  const int t    = threadIdx.x;
  const int lane = t & 63;
  const int w    = t >> 6;
  const int l15  = lane & 15;
  const int lq8  = (lane >> 4) * 8;
  const int lq4  = (lane >> 4) * 4;
  const int r0   = by * 128;
  const int c0   = bx * 128;
  const int wm   = w >> 1, wn = w & 1;

  f32x4 acc[4][4] = {};

  // prologue: prefetch k0=0 into buffer 0
#pragma unroll
  for (int i = 0; i < 4; ++i) {
    const int g = w * 4 + i;
    const unsigned short* src = (g < 8) ? A : Bt;
    const int rbase = (g < 8) ? (r0 + g * 16) : (c0 + (g - 8) * 16);
    g2l16(src + (size_t)(rbase + l15) * K + lq8, lds + g * 1024 + lane * 16);
  }

  int pb = 0;
  for (int k0 = 0; k0 < K; k0 += 32, pb ^= 1) {
    __syncthreads();   // cur buffer's g2l drained (issued one compute-phase ago)
    char* buf = lds + pb * 16384;
    if (k0 + 32 < K) {
      char* nbuf = lds + (pb ^ 1) * 16384;
#pragma unroll
      for (int i = 0; i < 4; ++i) {
        const int g = w * 4 + i;
        const unsigned short* src = (g < 8) ? A : Bt;
        const int rbase = (g < 8) ? (r0 + g * 16) : (c0 + (g - 8) * 16);
        g2l16(src + (size_t)(rbase + l15) * K + k0 + 32 + lq8, nbuf + g * 1024 + lane * 16);
      }
    }
    bf16x8 af[4], bfr[4];
#pragma unroll
    for (int i = 0; i < 4; ++i) af[i]  = *(const bf16x8*)(buf + (wm*4 + i) * 1024 + lane * 16);
#pragma unroll
    for (int j = 0; j < 4; ++j) bfr[j] = *(const bf16x8*)(buf + 8192 + (wn*4 + j) * 1024 + lane * 16);
#pragma unroll
    for (int i = 0; i < 4; ++i)
#pragma unroll
      for (int j = 0; j < 4; ++j)
        acc[i][j] = __builtin_amdgcn_mfma_f32_16x16x32_bf16(af[i], bfr[j], acc[i][j], 0, 0, 0);
  }

#pragma unroll
  for (int j = 0; j < 4; ++j) {
    const int col = c0 + wn * 64 + j * 16 + l15;
    const float bcol = bias[col];
#pragma unroll
    for (int i = 0; i < 4; ++i) {
      const int row = r0 + wm * 64 + i * 16 + lq4;
      if (mode == 0) {
        float* out = (float*)Cout;
#pragma unroll
        for (int r = 0; r < 4; ++r) out[(size_t)(row + r) * N + col] = acc[i][j][r] + bcol;
      } else if (mode == 1) {
        unsigned short* out = (unsigned short*)Cout;
#pragma unroll
        for (int r = 0; r < 4; ++r) out[(size_t)(row + r) * N + col] = f2bf((acc[i][j][r] + bcol) * scale);
      } else {
        unsigned short* out = (unsigned short*)Cout;
        const int bb = row >> 11;            // kLK = 2048
        const int lk = row & 2047;
        ushort4 o;
        o.x = f2bf(acc[i][j][0] + bcol); o.y = f2bf(acc[i][j][1] + bcol);
        o.z = f2bf(acc[i][j][2] + bcol); o.w = f2bf(acc[i][j][3] + bcol);
        *(ushort4*)(out + (size_t)(bb * kH + col) * kLK + lk) = o;
      }
    }
  }
}

// fused Q/K/V projections, XCD-swizzled (nwg=1280, 160/XCD):
// logical 0..255 Q | 256..767 K | 768..1279 V. Within each XCD chunk,
// consecutive logical ids share A-panels (bx minor) and weights L2-fit.
// Q projection pre-scaled by log2(e)/sqrt(HD) so attn exp2 needs no multiply.
__global__ __launch_bounds__(256) void qkv_gemm_kernel(
    const unsigned short* __restrict__ qA, const unsigned short* __restrict__ WqT,
    const float* __restrict__ bq, unsigned short* __restrict__ Qb,
    const unsigned short* __restrict__ kA, const unsigned short* __restrict__ WkT,
    const float* __restrict__ bk, unsigned short* __restrict__ Kb,
    const unsigned short* __restrict__ vA, const unsigned short* __restrict__ WvT,
    const float* __restrict__ bv, unsigned short* __restrict__ Vtw)
{
  __shared__ __align__(16) char lds[32768];
  const int bid = blockIdx.x;
  int id = (bid & 7) * 160 + (bid >> 3);   // bijective XCD swizzle
  if (id < 256) {
    gemm_body(qA, WqT, bq, Qb, 1024, 768, id & 7, id >> 3, 1,
              0.18033688011112042f, lds);   // log2(e)/8
  } else if (id < 768) {
    id -= 256;
    gemm_body(kA, WkT, bk, Kb, 1024, 512, id & 7, id >> 3, 1, 1.f, lds);
  } else {
    id -= 768;
    gemm_body(vA, WvT, bv, Vtw, 1024, 512, id & 7, id >> 3, 2, 1.f, lds);
  }
}

// out projection: fp32 out, 256 blocks (8 x 32 tiles of 128x128), XCD-swizzled
__global__ __launch_bounds__(256) void out_gemm_kernel(
    const unsigned short* __restrict__ A, const unsigned short* __restrict__ Bt,
    const float* __restrict__ bias, float* __restrict__ C)
{
  __shared__ __align__(16) char lds[32768];
  const int bid = blockIdx.x;
  const int id = (bid & 7) * 32 + (bid >> 3);   // bijective XCD swizzle, nwg=256
  gemm_body(A, Bt, bias, C, 1024, 1024, id & 7, id >> 3, 0, 1.f, lds);
}

// --------------------- MFMA flash attention (bf16, fp32 acc) -----------------
// Q [B*LQ, H] (pre-scaled by log2e/8), K [B*LK, H], Vt [B*H, LK], O [B*LQ, H].
// 128 q-rows/block, 4 waves x 32 q-rows; kc-tile = 64, double-buffered K/V via
// g2l prefetch pipeline (1 barrier/iter). Grid flat = qb*64 + bh: same-(b,h)
// blocks land on the same XCD (bid%8 == bh%8) -> K/V slice stays in one L2.
// QK^T is computed SWAPPED (mfma(K,Q) = S^T) so each lane holds 4 consecutive
// kc of one q-row -> P packs into 8 ds_write_b64/iter (was 32 ds_write_b16).
// P LDS layout [q][kc] stride 72 bf16 is unchanged, so PV reads are identical.
__global__ __launch_bounds__(256) void attn_mfma_kernel(
    const unsigned short* __restrict__ Q, const unsigned short* __restrict__ K,
    const unsigned short* __restrict__ Vt, unsigned short* __restrict__ O)
{
  // buf p at p*16384: K tile [0,8K) + V tile [8K,16K). P at 32768 (128 x 72 bf16)
  __shared__ __align__(16) char lds[51200];
  constexpr int POFF = 32768;
  const int t    = threadIdx.x;
  const int lane = t & 63;
  const int w    = t >> 6;
  const int l15  = lane & 15;
  const int lg   = lane >> 4;
  const int lq8  = lg * 8;
  const int lq4  = lg * 4;
  const int flat = blockIdx.x;
  const int bh   = flat & 63;
  const int qb   = flat >> 6;
  const int h    = bh & 15;
  const int b    = bh >> 4;
  const int q0   = qb * 128;
  const int hoff = h * kHD;

  bf16x8 qf[2][2];
#pragma unroll
  for (int qi = 0; qi < 2; ++qi)
#pragma unroll
    for (int kh = 0; kh < 2; ++kh)
      qf[qi][kh] = *(const bf16x8*)(Q + (size_t)(b*kLQ + q0 + w*32 + qi*16 + l15) * kH
                                      + hoff + kh*32 + lq8);

  f32x4 acc[2][4] = {};
  float lsum[2] = {0.f, 0.f};

  // P store base: row q = w*32 + qi*16 + l15, cols kcf*16 + lq4 .. +3
  char* const pwr = lds + POFF + (w*32 + l15) * 144 + lq4 * 2;
  // P read base: row q = w*32 + qi*16 + l15, cols kq*32 + lq8 .. +7
  const char* const prd = lds + POFF + (w*32 + l15) * 144 + lq8 * 2;

  // prologue: prefetch tile 0 into buffer 0
#pragma unroll
  for (int i = 0; i < 4; ++i) {
    const int g = w * 4 + i;
    if (g < 8) {
      g2l16(K + (size_t)(b*kLK + (g >> 1)*16 + l15) * kH + hoff + (g & 1)*32 + lq8,
            lds + g * 1024 + lane * 16);
    } else {
      const int gg = g - 8;
      g2l16(Vt + (size_t)(b*kH + hoff + (gg >> 1)*16 + l15) * kLK + (gg & 1)*32 + lq8,
            lds + 8192 + gg * 1024 + lane * 16);
    }
  }

  int pb = 0;
  for (int kt = 0; kt < kLK / 64; ++kt, pb ^= 1) {
    __syncthreads();   // cur buffer ready (g2l issued one compute-phase ago)
    char* buf = lds + pb * 16384;
    if (kt + 1 < kLK / 64) {
      char* nbuf = lds + (pb ^ 1) * 16384;
      const int kc1 = (kt + 1) * 64;
#pragma unroll
      for (int i = 0; i < 4; ++i) {
        const int g = w * 4 + i;
        if (g < 8) {
          g2l16(K + (size_t)(b*kLK + kc1 + (g >> 1)*16 + l15) * kH + hoff + (g & 1)*32 + lq8,
                nbuf + g * 1024 + lane * 16);
        } else {
          const int gg = g - 8;
          g2l16(Vt + (size_t)(b*kH + hoff + (gg >> 1)*16 + l15) * kLK + kc1 + (gg & 1)*32 + lq8,
                nbuf + 8192 + gg * 1024 + lane * 16);
        }
      }
    }

    // S^T = K Q^T : lane holds S[kc = kcf*16+lq4+r][q = w*32+qi*16+l15]
    f32x4 s[2][4];
#pragma unroll
    for (int kcf = 0; kcf < 4; ++kcf) {
      const bf16x8 kf0 = *(const bf16x8*)(buf + (kcf*2 + 0) * 1024 + lane * 16);
      const bf16x8 kf1 = *(const bf16x8*)(buf + (kcf*2 + 1) * 1024 + lane * 16);
#pragma unroll
      for (int qi = 0; qi < 2; ++qi) {
        f32x4 z = {};
        z = __builtin_amdgcn_mfma_f32_16x16x32_bf16(kf0, qf[qi][0], z, 0, 0, 0);
        z = __builtin_amdgcn_mfma_f32_16x16x32_bf16(kf1, qf[qi][1], z, 0, 0, 0);
        s[qi][kcf] = z;
      }
    }

    // P = exp2(s) (Q pre-scaled); pack 4 kc -> one b64 store per (qi,kcf).
    // bf16 by truncation (bias cancels via norm), packed with v_perm.
#pragma unroll
    for (int qi = 0; qi < 2; ++qi)
#pragma unroll
      for (int kcf = 0; kcf < 4; ++kcf) {
        const float p0 = __builtin_amdgcn_exp2f(s[qi][kcf][0]);
        const float p1 = __builtin_amdgcn_exp2f(s[qi][kcf][1]);
        const float p2 = __builtin_amdgcn_exp2f(s[qi][kcf][2]);
        const float p3 = __builtin_amdgcn_exp2f(s[qi][kcf][3]);
        lsum[qi] += (p0 + p1) + (p2 + p3);
        u32x2 pw;
        pw.x = __builtin_amdgcn_perm(__float_as_uint(p1), __float_as_uint(p0), 0x07060302u);
        pw.y = __builtin_amdgcn_perm(__float_as_uint(p3), __float_as_uint(p2), 0x07060302u);
        *(u32x2*)(pwr + qi*2304 + kcf*32) = pw;
      }

    // O += P V (P rows per-wave-private; no barrier needed)
    bf16x8 pf[2][2];
#pragma unroll
    for (int qi = 0; qi < 2; ++qi)
#pragma unroll
      for (int kq = 0; kq < 2; ++kq)
        pf[qi][kq] = *(const bf16x8*)(prd + qi*2304 + kq*64);
#pragma unroll
    for (int vd = 0; vd < 4; ++vd) {
      const bf16x8 vf0 = *(const bf16x8*)(buf + 8192 + (vd*2 + 0) * 1024 + lane * 16);
      const bf16x8 vf1 = *(const bf16x8*)(buf + 8192 + (vd*2 + 1) * 1024 + lane * 16);
#pragma unroll
      for (int qi = 0; qi < 2; ++qi) {
        acc[qi][vd] = __builtin_amdgcn_mfma_f32_16x16x32_bf16(pf[qi][0], vf0, acc[qi][vd], 0, 0, 0);
        acc[qi][vd] = __builtin_amdgcn_mfma_f32_16x16x32_bf16(pf[qi][1], vf1, acc[qi][vd], 0, 0, 0);
      }
    }
  }

  // row sums: lane holds partial for q = l15 over its kc slice; reduce across
  // the 4 lane-groups, then redistribute 1/sum to acc row owners (q = lq4+r).
  float rinv[2][4];
#pragma unroll
  for (int qi = 0; qi < 2; ++qi) {
    float v = lsum[qi];
    v += __shfl_xor(v, 16);
    v += __shfl_xor(v, 32);
    v = 1.f / v;
#pragma unroll
    for (int r = 0; r < 4; ++r) rinv[qi][r] = __shfl(v, lq4 + r);
  }
#pragma unroll
  for (int qi = 0; qi < 2; ++qi)
#pragma unroll
    for (int vd = 0; vd < 4; ++vd)
#pragma unroll
      for (int r = 0; r < 4; ++r)
        O[(size_t)(b*kLQ + q0 + w*32 + qi*16 + lq4 + r) * kH + hoff + vd*16 + l15] =
            f2bf(acc[qi][vd][r] * rinv[qi][r]);
}

extern "C" void kernel_launch(void* const* d_in, const int* in_sizes, int n_in,
                              void* d_out, int out_size, void* d_ws, size_t ws_size,
                              hipStream_t stream) {
  (void)in_sizes; (void)n_in; (void)out_size; (void)ws_size;
  const float* query = (const float*)d_in[0];
  const float* key   = (const float*)d_in[1];
  const float* value = (const float*)d_in[2];
  const float* Wq = (const float*)d_in[3];
  const float* bq = (const float*)d_in[4];
  const float* Wk = (const float*)d_in[5];
  const float* bk = (const float*)d_in[6];
  const float* Wv = (const float*)d_in[7];
  const float* bv = (const float*)d_in[8];
  const float* Wo = (const float*)d_in[9];
  const float* bo = (const float*)d_in[10];
  float* out = (float*)d_out;

  unsigned short* ws  = (unsigned short*)d_ws;
  unsigned short* qA  = ws;                  // 4*1024*768
  unsigned short* kA  = qA  + 3145728;       // 4*2048*512
  unsigned short* vA  = kA  + 4194304;
  unsigned short* WqT = vA  + 4194304;       // 1024*768
  unsigned short* WkT = WqT + 786432;        // 1024*512
  unsigned short* WvT = WkT + 524288;
  unsigned short* WoT = WvT + 524288;        // 1024*1024
  unsigned short* Qb  = WoT + 1048576;       // 4096*1024
  unsigned short* Kb  = Qb  + 4194304;       // 8192*1024
  unsigned short* Vtw = Kb  + 8388608;       // 4096*2048 (transposed V)
  unsigned short* Ab  = Vtw + 8388608;       // 4096*1024

  prep_kernel<<<6336, 256, 0, stream>>>(query, key, value, Wq, Wk, Wv, Wo,
                                        qA, kA, vA, WqT, WkT, WvT, WoT);
  qkv_gemm_kernel<<<1280, 256, 0, stream>>>(qA, WqT, bq, Qb,
                                            kA, WkT, bk, Kb,
                                            vA, WvT, bv, Vtw);
  attn_mfma_kernel<<<512, 256, 0, stream>>>(Qb, Kb, Vtw, Ab);
  out_gemm_kernel<<<256, 256, 0, stream>>>(Ab, WoT, bo, out);
}

// Round 4
// 231.638 us; speedup vs baseline: 1.1274x; 1.1065x over previous
//
#include <hip/hip_runtime.h>
#include <math.h>

using bf16x8 = __attribute__((ext_vector_type(8))) short;
using f32x4  = __attribute__((ext_vector_type(4))) float;
using u32x2  = __attribute__((ext_vector_type(2))) unsigned int;

namespace {
constexpr int kB  = 4;
constexpr int kLQ = 1024;
constexpr int kLK = 2048;
constexpr int kH  = 1024;
constexpr int kHD = 64;
}

__device__ __forceinline__ unsigned short f2bf(float x) {
  union { float f; unsigned int u; } v; v.f = x;
  unsigned int r = v.u + 0x7fffu + ((v.u >> 16) & 1u);   // RNE
  return (unsigned short)(r >> 16);
}

// async global->LDS 16B copy
typedef const __attribute__((address_space(1))) unsigned int guint_t;
typedef __attribute__((address_space(3))) unsigned int luint_t;
__device__ __forceinline__ void g2l16(const void* g, void* l) {
  __builtin_amdgcn_global_load_lds(
      (guint_t*)g,
      (luint_t*)(unsigned int)(unsigned long long)l,
      16, 0, 0);
}

// --------- fused prep: fp32->bf16 casts (q,k,v) + 4 weight transposes --------
__global__ __launch_bounds__(256) void prep_kernel(
    const float* __restrict__ q, const float* __restrict__ k,
    const float* __restrict__ v, const float* __restrict__ Wq,
    const float* __restrict__ Wk, const float* __restrict__ Wv,
    const float* __restrict__ Wo, unsigned short* __restrict__ qo,
    unsigned short* __restrict__ ko, unsigned short* __restrict__ vo,
    unsigned short* __restrict__ WqT, unsigned short* __restrict__ WkT,
    unsigned short* __restrict__ WvT, unsigned short* __restrict__ WoT)
{
  __shared__ float tile[64][65];
  const int t = threadIdx.x;
  if (blockIdx.x < 5632) {
    int c = blockIdx.x * 256 + t;
    const float* src; unsigned short* dst;
    if (c < 393216)      { src = q; dst = qo; }
    else if (c < 917504) { src = k; dst = ko; c -= 393216; }
    else                 { src = v; dst = vo; c -= 917504; }
    const int i = c * 8;
    const float4 a = *(const float4*)(src + i);
    const float4 b = *(const float4*)(src + i + 4);
    uint4 o;
    o.x = (unsigned int)f2bf(a.x) | ((unsigned int)f2bf(a.y) << 16);
    o.y = (unsigned int)f2bf(a.z) | ((unsigned int)f2bf(a.w) << 16);
    o.z = (unsigned int)f2bf(b.x) | ((unsigned int)f2bf(b.y) << 16);
    o.w = (unsigned int)f2bf(b.z) | ((unsigned int)f2bf(b.w) << 16);
    *(uint4*)(dst + i) = o;
    return;
  }
  int id = blockIdx.x - 5632;
  const float* W; unsigned short* Wt; int Kd;
  if (id < 192)      { W = Wq; Wt = WqT; Kd = 768; }
  else if (id < 320) { W = Wk; Wt = WkT; Kd = 512;  id -= 192; }
  else if (id < 448) { W = Wv; Wt = WvT; Kd = 512;  id -= 320; }
  else               { W = Wo; Wt = WoT; Kd = 1024; id -= 448; }
  const int Nd = 1024;
  const int n0 = (id & 15) * 64;
  const int k0 = (id >> 4) * 64;
  const int rr = t >> 4;
  const int c4 = t & 15;
#pragma unroll
  for (int i = 0; i < 4; ++i) {
    const int row = i * 16 + rr;
    const float4 vv = *(const float4*)(W + (size_t)(k0 + row) * Nd + n0 + c4 * 4);
    tile[row][c4*4+0] = vv.x; tile[row][c4*4+1] = vv.y;
    tile[row][c4*4+2] = vv.z; tile[row][c4*4+3] = vv.w;
  }
  __syncthreads();
#pragma unroll
  for (int i = 0; i < 4; ++i) {
    const int n = i * 16 + rr;
    ushort4 o;
    o.x = f2bf(tile[c4*4+0][n]); o.y = f2bf(tile[c4*4+1][n]);
    o.z = f2bf(tile[c4*4+2][n]); o.w = f2bf(tile[c4*4+3][n]);
    *(ushort4*)(Wt + (size_t)(n0 + n) * Kd + k0 + c4 * 4) = o;
  }
}

// ---- GEMM body: 128x128 tile, BK=32, TRIPLE-buffered counted-vmcnt pipeline -
// Raw `s_waitcnt vmcnt(4); s_barrier` waits only the CURRENT tile's 4 g2l per
// thread, leaving the next tile's 4 in flight across the barrier (T4). Each
// tile's loads get ~2 compute phases of latency cover. WAR on slot (t+2)%3 is
// ordered by the iteration-t barrier (slot last read in iteration t-1).
// mode 0: fp32 out. mode 1: bf16 out, (acc+bias)*scale. mode 2: bf16 out V-T.
__device__ __forceinline__ void gemm_body(
    const unsigned short* __restrict__ A, const unsigned short* __restrict__ Bt,
    const float* __restrict__ bias, void* __restrict__ Cout,
    int N, int K, int bx, int by, int mode, float scale, char* lds)
{
  const int t    = threadIdx.x;
  const int lane = t & 63;
  const int w    = t >> 6;
  const int l15  = lane & 15;
  const int lq8  = (lane >> 4) * 8;
  const int lq4  = (lane >> 4) * 4;
  const int r0   = by * 128;
  const int c0   = bx * 128;
  const int wm   = w >> 1, wn = w & 1;

  f32x4 acc[4][4] = {};

  // per-thread staging addresses (4 g2l per K-tile)
  const unsigned short* gsrc[4];
  char* ldst[4];
#pragma unroll
  for (int i = 0; i < 4; ++i) {
    const int g = w * 4 + i;
    const unsigned short* src = (g < 8) ? A : Bt;
    const int rbase = (g < 8) ? (r0 + g * 16) : (c0 + (g - 8) * 16);
    gsrc[i] = src + (size_t)(rbase + l15) * K + lq8;
    ldst[i] = lds + g * 1024 + lane * 16;
  }

  // prologue: tile 0 -> slot 0, tile 1 -> slot 1
#pragma unroll
  for (int i = 0; i < 4; ++i) g2l16(gsrc[i], ldst[i]);
#pragma unroll
  for (int i = 0; i < 4; ++i) g2l16(gsrc[i] + 32, ldst[i] + 16384);

  int slot = 0;
  for (int k0 = 0; k0 < K; k0 += 32) {
    // wait for current tile only; keep next tile's loads in flight
    if (k0 + 32 < K) {
      asm volatile("s_waitcnt vmcnt(4)\n\ts_barrier" ::: "memory");
    } else {
      asm volatile("s_waitcnt vmcnt(0)\n\ts_barrier" ::: "memory");
    }
    char* buf = lds + slot * 16384;
    if (k0 + 64 < K) {
      int ns = slot + 2; if (ns >= 3) ns -= 3;   // slot of tile t+2
      char* noff = ldst[0] - (lds + 0) + (char*)0; (void)noff;
#pragma unroll
      for (int i = 0; i < 4; ++i)
        g2l16(gsrc[i] + k0 + 64, ldst[i] + ns * 16384);
    }
    bf16x8 af[4], bfr[4];
#pragma unroll
    for (int i = 0; i < 4; ++i) af[i]  = *(const bf16x8*)(buf + (wm*4 + i) * 1024 + lane * 16);
#pragma unroll
    for (int j = 0; j < 4; ++j) bfr[j] = *(const bf16x8*)(buf + 8192 + (wn*4 + j) * 1024 + lane * 16);
#pragma unroll
    for (int i = 0; i < 4; ++i)
#pragma unroll
      for (int j = 0; j < 4; ++j)
        acc[i][j] = __builtin_amdgcn_mfma_f32_16x16x32_bf16(af[i], bfr[j], acc[i][j], 0, 0, 0);
    slot = (slot == 2) ? 0 : slot + 1;
  }

#pragma unroll
  for (int j = 0; j < 4; ++j) {
    const int col = c0 + wn * 64 + j * 16 + l15;
    const float bcol = bias[col];
#pragma unroll
    for (int i = 0; i < 4; ++i) {
      const int row = r0 + wm * 64 + i * 16 + lq4;
      if (mode == 0) {
        float* out = (float*)Cout;
#pragma unroll
        for (int r = 0; r < 4; ++r) out[(size_t)(row + r) * N + col] = acc[i][j][r] + bcol;
      } else if (mode == 1) {
        unsigned short* out = (unsigned short*)Cout;
#pragma unroll
        for (int r = 0; r < 4; ++r) out[(size_t)(row + r) * N + col] = f2bf((acc[i][j][r] + bcol) * scale);
      } else {
        unsigned short* out = (unsigned short*)Cout;
        const int bb = row >> 11;            // kLK = 2048
        const int lk = row & 2047;
        ushort4 o;
        o.x = f2bf(acc[i][j][0] + bcol); o.y = f2bf(acc[i][j][1] + bcol);
        o.z = f2bf(acc[i][j][2] + bcol); o.w = f2bf(acc[i][j][3] + bcol);
        *(ushort4*)(out + (size_t)(bb * kH + col) * kLK + lk) = o;
      }
    }
  }
}

// fused Q/K/V projections: blocks 0..255 Q | 256..767 K | 768..1279 V.
// UNSWIZZLED (R3 A/B: default bx=id&7 round-robin already pins one B-panel
// per XCD L2; swizzle regressed 62->80us). Q pre-scaled by log2(e)/sqrt(HD).
__global__ __launch_bounds__(256) void qkv_gemm_kernel(
    const unsigned short* __restrict__ qA, const unsigned short* __restrict__ WqT,
    const float* __restrict__ bq, unsigned short* __restrict__ Qb,
    const unsigned short* __restrict__ kA, const unsigned short* __restrict__ WkT,
    const float* __restrict__ bk, unsigned short* __restrict__ Kb,
    const unsigned short* __restrict__ vA, const unsigned short* __restrict__ WvT,
    const float* __restrict__ bv, unsigned short* __restrict__ Vtw)
{
  __shared__ __align__(16) char lds[49152];
  int id = blockIdx.x;
  if (id < 256) {
    gemm_body(qA, WqT, bq, Qb, 1024, 768, id & 7, id >> 3, 1,
              0.18033688011112042f, lds);   // log2(e)/8
  } else if (id < 768) {
    id -= 256;
    gemm_body(kA, WkT, bk, Kb, 1024, 512, id & 7, id >> 3, 1, 1.f, lds);
  } else {
    id -= 768;
    gemm_body(vA, WvT, bv, Vtw, 1024, 512, id & 7, id >> 3, 2, 1.f, lds);
  }
}

// out projection: fp32 out, 256 blocks (8 x 32 tiles of 128x128), unswizzled
__global__ __launch_bounds__(256) void out_gemm_kernel(
    const unsigned short* __restrict__ A, const unsigned short* __restrict__ Bt,
    const float* __restrict__ bias, float* __restrict__ C)
{
  __shared__ __align__(16) char lds[49152];
  const int id = blockIdx.x;
  gemm_body(A, Bt, bias, C, 1024, 1024, id & 7, id >> 3, 0, 1.f, lds);
}

// --------------------- MFMA flash attention (bf16, fp32 acc) -----------------
// Q [B*LQ, H] (pre-scaled by log2e/8), K [B*LK, H], Vt [B*H, LK], O [B*LQ, H].
// 128 q-rows/block, 4 waves x 32 q-rows; kc-tile = 64, double-buffered K/V via
// g2l prefetch pipeline (1 barrier/iter). Grid flat = qb*64 + bh: same-(b,h)
// blocks land on the same XCD (bid%8 == bh%8) -> K/V slice stays in one L2.
// QK^T is computed SWAPPED (mfma(K,Q) = S^T) so each lane holds 4 consecutive
// kc of one q-row -> P packs into 8 ds_write_b64/iter (was 32 ds_write_b16).
// P LDS layout [q][kc] stride 72 bf16 is unchanged, so PV reads are identical.
__global__ __launch_bounds__(256) void attn_mfma_kernel(
    const unsigned short* __restrict__ Q, const unsigned short* __restrict__ K,
    const unsigned short* __restrict__ Vt, unsigned short* __restrict__ O)
{
  // buf p at p*16384: K tile [0,8K) + V tile [8K,16K). P at 32768 (128 x 72 bf16)
  __shared__ __align__(16) char lds[51200];
  constexpr int POFF = 32768;
  const int t    = threadIdx.x;
  const int lane = t & 63;
  const int w    = t >> 6;
  const int l15  = lane & 15;
  const int lg   = lane >> 4;
  const int lq8  = lg * 8;
  const int lq4  = lg * 4;
  const int flat = blockIdx.x;
  const int bh   = flat & 63;
  const int qb   = flat >> 6;
  const int h    = bh & 15;
  const int b    = bh >> 4;
  const int q0   = qb * 128;
  const int hoff = h * kHD;

  bf16x8 qf[2][2];
#pragma unroll
  for (int qi = 0; qi < 2; ++qi)
#pragma unroll
    for (int kh = 0; kh < 2; ++kh)
      qf[qi][kh] = *(const bf16x8*)(Q + (size_t)(b*kLQ + q0 + w*32 + qi*16 + l15) * kH
                                      + hoff + kh*32 + lq8);

  f32x4 acc[2][4] = {};
  float lsum[2] = {0.f, 0.f};

  // P store base: row q = w*32 + qi*16 + l15, cols kcf*16 + lq4 .. +3
  char* const pwr = lds + POFF + (w*32 + l15) * 144 + lq4 * 2;
  // P read base: row q = w*32 + qi*16 + l15, cols kq*32 + lq8 .. +7
  const char* const prd = lds + POFF + (w*32 + l15) * 144 + lq8 * 2;

  // prologue: prefetch tile 0 into buffer 0
#pragma unroll
  for (int i = 0; i < 4; ++i) {
    const int g = w * 4 + i;
    if (g < 8) {
      g2l16(K + (size_t)(b*kLK + (g >> 1)*16 + l15) * kH + hoff + (g & 1)*32 + lq8,
            lds + g * 1024 + lane * 16);
    } else {
      const int gg = g - 8;
      g2l16(Vt + (size_t)(b*kH + hoff + (gg >> 1)*16 + l15) * kLK + (gg & 1)*32 + lq8,
            lds + 8192 + gg * 1024 + lane * 16);
    }
  }

  int pb = 0;
  for (int kt = 0; kt < kLK / 64; ++kt, pb ^= 1) {
    __syncthreads();   // cur buffer ready (g2l issued one compute-phase ago)
    char* buf = lds + pb * 16384;
    if (kt + 1 < kLK / 64) {
      char* nbuf = lds + (pb ^ 1) * 16384;
      const int kc1 = (kt + 1) * 64;
#pragma unroll
      for (int i = 0; i < 4; ++i) {
        const int g = w * 4 + i;
        if (g < 8) {
          g2l16(K + (size_t)(b*kLK + kc1 + (g >> 1)*16 + l15) * kH + hoff + (g & 1)*32 + lq8,
                nbuf + g * 1024 + lane * 16);
        } else {
          const int gg = g - 8;
          g2l16(Vt + (size_t)(b*kH + hoff + (gg >> 1)*16 + l15) * kLK + kc1 + (gg & 1)*32 + lq8,
                nbuf + 8192 + gg * 1024 + lane * 16);
        }
      }
    }

    // S^T = K Q^T : lane holds S[kc = kcf*16+lq4+r][q = w*32+qi*16+l15]
    f32x4 s[2][4];
#pragma unroll
    for (int kcf = 0; kcf < 4; ++kcf) {
      const bf16x8 kf0 = *(const bf16x8*)(buf + (kcf*2 + 0) * 1024 + lane * 16);
      const bf16x8 kf1 = *(const bf16x8*)(buf + (kcf*2 + 1) * 1024 + lane * 16);
#pragma unroll
      for (int qi = 0; qi < 2; ++qi) {
        f32x4 z = {};
        z = __builtin_amdgcn_mfma_f32_16x16x32_bf16(kf0, qf[qi][0], z, 0, 0, 0);
        z = __builtin_amdgcn_mfma_f32_16x16x32_bf16(kf1, qf[qi][1], z, 0, 0, 0);
        s[qi][kcf] = z;
      }
    }

    // P = exp2(s) (Q pre-scaled); pack 4 kc -> one b64 store per (qi,kcf).
    // bf16 by truncation (bias cancels via norm), packed with v_perm.
#pragma unroll
    for (int qi = 0; qi < 2; ++qi)
#pragma unroll
      for (int kcf = 0; kcf < 4; ++kcf) {
        const float p0 = __builtin_amdgcn_exp2f(s[qi][kcf][0]);
        const float p1 = __builtin_amdgcn_exp2f(s[qi][kcf][1]);
        const float p2 = __builtin_amdgcn_exp2f(s[qi][kcf][2]);
        const float p3 = __builtin_amdgcn_exp2f(s[qi][kcf][3]);
        lsum[qi] += (p0 + p1) + (p2 + p3);
        u32x2 pw;
        pw.x = __builtin_amdgcn_perm(__float_as_uint(p1), __float_as_uint(p0), 0x07060302u);
        pw.y = __builtin_amdgcn_perm(__float_as_uint(p3), __float_as_uint(p2), 0x07060302u);
        *(u32x2*)(pwr + qi*2304 + kcf*32) = pw;
      }

    // O += P V (P rows per-wave-private; no barrier needed)
    bf16x8 pf[2][2];
#pragma unroll
    for (int qi = 0; qi < 2; ++qi)
#pragma unroll
      for (int kq = 0; kq < 2; ++kq)
        pf[qi][kq] = *(const bf16x8*)(prd + qi*2304 + kq*64);
#pragma unroll
    for (int vd = 0; vd < 4; ++vd) {
      const bf16x8 vf0 = *(const bf16x8*)(buf + 8192 + (vd*2 + 0) * 1024 + lane * 16);
      const bf16x8 vf1 = *(const bf16x8*)(buf + 8192 + (vd*2 + 1) * 1024 + lane * 16);
#pragma unroll
      for (int qi = 0; qi < 2; ++qi) {
        acc[qi][vd] = __builtin_amdgcn_mfma_f32_16x16x32_bf16(pf[qi][0], vf0, acc[qi][vd], 0, 0, 0);
        acc[qi][vd] = __builtin_amdgcn_mfma_f32_16x16x32_bf16(pf[qi][1], vf1, acc[qi][vd], 0, 0, 0);
      }
    }
  }

  // row sums: lane holds partial for q = l15 over its kc slice; reduce across
  // the 4 lane-groups, then redistribute 1/sum to acc row owners (q = lq4+r).
  float rinv[2][4];
#pragma unroll
  for (int qi = 0; qi < 2; ++qi) {
    float v = lsum[qi];
    v += __shfl_xor(v, 16);
    v += __shfl_xor(v, 32);
    v = 1.f / v;
#pragma unroll
    for (int r = 0; r < 4; ++r) rinv[qi][r] = __shfl(v, lq4 + r);
  }
#pragma unroll
  for (int qi = 0; qi < 2; ++qi)
#pragma unroll
    for (int vd = 0; vd < 4; ++vd)
#pragma unroll
      for (int r = 0; r < 4; ++r)
        O[(size_t)(b*kLQ + q0 + w*32 + qi*16 + lq4 + r) * kH + hoff + vd*16 + l15] =
            f2bf(acc[qi][vd][r] * rinv[qi][r]);
}

extern "C" void kernel_launch(void* const* d_in, const int* in_sizes, int n_in,
                              void* d_out, int out_size, void* d_ws, size_t ws_size,
                              hipStream_t stream) {
  (void)in_sizes; (void)n_in; (void)out_size; (void)ws_size;
  const float* query = (const float*)d_in[0];
  const float* key   = (const float*)d_in[1];
  const float* value = (const float*)d_in[2];
  const float* Wq = (const float*)d_in[3];
  const float* bq = (const float*)d_in[4];
  const float* Wk = (const float*)d_in[5];
  const float* bk = (const float*)d_in[6];
  const float* Wv = (const float*)d_in[7];
  const float* bv = (const float*)d_in[8];
  const float* Wo = (const float*)d_in[9];
  const float* bo = (const float*)d_in[10];
  float* out = (float*)d_out;

  unsigned short* ws  = (unsigned short*)d_ws;
  unsigned short* qA  = ws;                  // 4*1024*768
  unsigned short* kA  = qA  + 3145728;       // 4*2048*512
  unsigned short* vA  = kA  + 4194304;
  unsigned short* WqT = vA  + 4194304;       // 1024*768
  unsigned short* WkT = WqT + 786432;        // 1024*512
  unsigned short* WvT = WkT + 524288;
  unsigned short* WoT = WvT + 524288;        // 1024*1024
  unsigned short* Qb  = WoT + 1048576;       // 4096*1024
  unsigned short* Kb  = Qb  + 4194304;       // 8192*1024
  unsigned short* Vtw = Kb  + 8388608;       // 4096*2048 (transposed V)
  unsigned short* Ab  = Vtw + 8388608;       // 4096*1024

  prep_kernel<<<6336, 256, 0, stream>>>(query, key, value, Wq, Wk, Wv, Wo,
                                        qA, kA, vA, WqT, WkT, WvT, WoT);
  qkv_gemm_kernel<<<1280, 256, 0, stream>>>(qA, WqT, bq, Qb,
                                            kA, WkT, bk, Kb,
                                            vA, WvT, bv, Vtw);
  attn_mfma_kernel<<<512, 256, 0, stream>>>(Qb, Kb, Vtw, Ab);
  out_gemm_kernel<<<256, 256, 0, stream>>>(Ab, WoT, bo, out);
}

// Round 5
// 230.244 us; speedup vs baseline: 1.1342x; 1.0061x over previous
//
#include <hip/hip_runtime.h>
#include <math.h>

using bf16x8 = __attribute__((ext_vector_type(8))) short;
using f32x4  = __attribute__((ext_vector_type(4))) float;
using u32x2  = __attribute__((ext_vector_type(2))) unsigned int;

namespace {
constexpr int kB  = 4;
constexpr int kLQ = 1024;
constexpr int kLK = 2048;
constexpr int kH  = 1024;
constexpr int kHD = 64;
}

__device__ __forceinline__ unsigned short f2bf(float x) {
  union { float f; unsigned int u; } v; v.f = x;
  unsigned int r = v.u + 0x7fffu + ((v.u >> 16) & 1u);   // RNE
  return (unsigned short)(r >> 16);
}

// async global->LDS 16B copy
typedef const __attribute__((address_space(1))) unsigned int guint_t;
typedef __attribute__((address_space(3))) unsigned int luint_t;
__device__ __forceinline__ void g2l16(const void* g, void* l) {
  __builtin_amdgcn_global_load_lds(
      (guint_t*)g,
      (luint_t*)(unsigned int)(unsigned long long)l,
      16, 0, 0);
}

// --------- fused prep: fp32->bf16 casts (q,k,v) + 4 weight transposes --------
__global__ __launch_bounds__(256) void prep_kernel(
    const float* __restrict__ q, const float* __restrict__ k,
    const float* __restrict__ v, const float* __restrict__ Wq,
    const float* __restrict__ Wk, const float* __restrict__ Wv,
    const float* __restrict__ Wo, unsigned short* __restrict__ qo,
    unsigned short* __restrict__ ko, unsigned short* __restrict__ vo,
    unsigned short* __restrict__ WqT, unsigned short* __restrict__ WkT,
    unsigned short* __restrict__ WvT, unsigned short* __restrict__ WoT)
{
  __shared__ float tile[64][65];
  const int t = threadIdx.x;
  if (blockIdx.x < 5632) {
    int c = blockIdx.x * 256 + t;
    const float* src; unsigned short* dst;
    if (c < 393216)      { src = q; dst = qo; }
    else if (c < 917504) { src = k; dst = ko; c -= 393216; }
    else                 { src = v; dst = vo; c -= 917504; }
    const int i = c * 8;
    const float4 a = *(const float4*)(src + i);
    const float4 b = *(const float4*)(src + i + 4);
    uint4 o;
    o.x = (unsigned int)f2bf(a.x) | ((unsigned int)f2bf(a.y) << 16);
    o.y = (unsigned int)f2bf(a.z) | ((unsigned int)f2bf(a.w) << 16);
    o.z = (unsigned int)f2bf(b.x) | ((unsigned int)f2bf(b.y) << 16);
    o.w = (unsigned int)f2bf(b.z) | ((unsigned int)f2bf(b.w) << 16);
    *(uint4*)(dst + i) = o;
    return;
  }
  int id = blockIdx.x - 5632;
  const float* W; unsigned short* Wt; int Kd;
  if (id < 192)      { W = Wq; Wt = WqT; Kd = 768; }
  else if (id < 320) { W = Wk; Wt = WkT; Kd = 512;  id -= 192; }
  else if (id < 448) { W = Wv; Wt = WvT; Kd = 512;  id -= 320; }
  else               { W = Wo; Wt = WoT; Kd = 1024; id -= 448; }
  const int Nd = 1024;
  const int n0 = (id & 15) * 64;
  const int k0 = (id >> 4) * 64;
  const int rr = t >> 4;
  const int c4 = t & 15;
#pragma unroll
  for (int i = 0; i < 4; ++i) {
    const int row = i * 16 + rr;
    const float4 vv = *(const float4*)(W + (size_t)(k0 + row) * Nd + n0 + c4 * 4);
    tile[row][c4*4+0] = vv.x; tile[row][c4*4+1] = vv.y;
    tile[row][c4*4+2] = vv.z; tile[row][c4*4+3] = vv.w;
  }
  __syncthreads();
#pragma unroll
  for (int i = 0; i < 4; ++i) {
    const int n = i * 16 + rr;
    ushort4 o;
    o.x = f2bf(tile[c4*4+0][n]); o.y = f2bf(tile[c4*4+1][n]);
    o.z = f2bf(tile[c4*4+2][n]); o.w = f2bf(tile[c4*4+3][n]);
    *(ushort4*)(Wt + (size_t)(n0 + n) * Kd + k0 + c4 * 4) = o;
  }
}

// ---- GEMM body: 128x128 tile, BK=32, TRIPLE-buffered counted-vmcnt pipeline -
// Raw `s_waitcnt vmcnt(4); s_barrier` waits only the CURRENT tile's 4 g2l per
// thread, leaving the next tile's 4 in flight across the barrier (T4). Each
// tile's loads get ~2 compute phases of latency cover. WAR on slot (t+2)%3 is
// ordered by the iteration-t barrier (slot last read in iteration t-1).
// mode 0: fp32 out. mode 1: bf16 out, (acc+bias)*scale. mode 2: bf16 out V-T.
__device__ __forceinline__ void gemm_body(
    const unsigned short* __restrict__ A, const unsigned short* __restrict__ Bt,
    const float* __restrict__ bias, void* __restrict__ Cout,
    int N, int K, int bx, int by, int mode, float scale, char* lds)
{
  const int t    = threadIdx.x;
  const int lane = t & 63;
  const int w    = t >> 6;
  const int l15  = lane & 15;
  const int lq8  = (lane >> 4) * 8;
  const int lq4  = (lane >> 4) * 4;
  const int r0   = by * 128;
  const int c0   = bx * 128;
  const int wm   = w >> 1, wn = w & 1;

  f32x4 acc[4][4] = {};

  // per-thread staging addresses (4 g2l per K-tile)
  const unsigned short* gsrc[4];
  char* ldst[4];
#pragma unroll
  for (int i = 0; i < 4; ++i) {
    const int g = w * 4 + i;
    const unsigned short* src = (g < 8) ? A : Bt;
    const int rbase = (g < 8) ? (r0 + g * 16) : (c0 + (g - 8) * 16);
    gsrc[i] = src + (size_t)(rbase + l15) * K + lq8;
    ldst[i] = lds + g * 1024 + lane * 16;
  }

  // prologue: tile 0 -> slot 0, tile 1 -> slot 1
#pragma unroll
  for (int i = 0; i < 4; ++i) g2l16(gsrc[i], ldst[i]);
#pragma unroll
  for (int i = 0; i < 4; ++i) g2l16(gsrc[i] + 32, ldst[i] + 16384);

  int slot = 0;
  for (int k0 = 0; k0 < K; k0 += 32) {
    // wait for current tile only; keep next tile's loads in flight
    if (k0 + 32 < K) {
      asm volatile("s_waitcnt vmcnt(4)\n\ts_barrier" ::: "memory");
    } else {
      asm volatile("s_waitcnt vmcnt(0)\n\ts_barrier" ::: "memory");
    }
    char* buf = lds + slot * 16384;
    if (k0 + 64 < K) {
      int ns = slot + 2; if (ns >= 3) ns -= 3;   // slot of tile t+2
#pragma unroll
      for (int i = 0; i < 4; ++i)
        g2l16(gsrc[i] + k0 + 64, ldst[i] + ns * 16384);
    }
    bf16x8 af[4], bfr[4];
#pragma unroll
    for (int i = 0; i < 4; ++i) af[i]  = *(const bf16x8*)(buf + (wm*4 + i) * 1024 + lane * 16);
#pragma unroll
    for (int j = 0; j < 4; ++j) bfr[j] = *(const bf16x8*)(buf + 8192 + (wn*4 + j) * 1024 + lane * 16);
#pragma unroll
    for (int i = 0; i < 4; ++i)
#pragma unroll
      for (int j = 0; j < 4; ++j)
        acc[i][j] = __builtin_amdgcn_mfma_f32_16x16x32_bf16(af[i], bfr[j], acc[i][j], 0, 0, 0);
    slot = (slot == 2) ? 0 : slot + 1;
  }

#pragma unroll
  for (int j = 0; j < 4; ++j) {
    const int col = c0 + wn * 64 + j * 16 + l15;
    const float bcol = bias[col];
#pragma unroll
    for (int i = 0; i < 4; ++i) {
      const int row = r0 + wm * 64 + i * 16 + lq4;
      if (mode == 0) {
        float* out = (float*)Cout;
#pragma unroll
        for (int r = 0; r < 4; ++r) out[(size_t)(row + r) * N + col] = acc[i][j][r] + bcol;
      } else if (mode == 1) {
        unsigned short* out = (unsigned short*)Cout;
#pragma unroll
        for (int r = 0; r < 4; ++r) out[(size_t)(row + r) * N + col] = f2bf((acc[i][j][r] + bcol) * scale);
      } else {
        unsigned short* out = (unsigned short*)Cout;
        const int bb = row >> 11;            // kLK = 2048
        const int lk = row & 2047;
        ushort4 o;
        o.x = f2bf(acc[i][j][0] + bcol); o.y = f2bf(acc[i][j][1] + bcol);
        o.z = f2bf(acc[i][j][2] + bcol); o.w = f2bf(acc[i][j][3] + bcol);
        *(ushort4*)(out + (size_t)(bb * kH + col) * kLK + lk) = o;
      }
    }
  }
}

// fused Q/K/V projections: blocks 0..255 Q | 256..767 K | 768..1279 V.
// UNSWIZZLED (R3 A/B: default bx=id&7 round-robin already pins one B-panel
// per XCD L2; swizzle regressed 62->80us). Q pre-scaled by log2(e)/sqrt(HD).
__global__ __launch_bounds__(256) void qkv_gemm_kernel(
    const unsigned short* __restrict__ qA, const unsigned short* __restrict__ WqT,
    const float* __restrict__ bq, unsigned short* __restrict__ Qb,
    const unsigned short* __restrict__ kA, const unsigned short* __restrict__ WkT,
    const float* __restrict__ bk, unsigned short* __restrict__ Kb,
    const unsigned short* __restrict__ vA, const unsigned short* __restrict__ WvT,
    const float* __restrict__ bv, unsigned short* __restrict__ Vtw)
{
  __shared__ __align__(16) char lds[49152];
  int id = blockIdx.x;
  if (id < 256) {
    gemm_body(qA, WqT, bq, Qb, 1024, 768, id & 7, id >> 3, 1,
              0.18033688011112042f, lds);   // log2(e)/8
  } else if (id < 768) {
    id -= 256;
    gemm_body(kA, WkT, bk, Kb, 1024, 512, id & 7, id >> 3, 1, 1.f, lds);
  } else {
    id -= 768;
    gemm_body(vA, WvT, bv, Vtw, 1024, 512, id & 7, id >> 3, 2, 1.f, lds);
  }
}

// out projection: fp32 out, 256 blocks (8 x 32 tiles of 128x128), unswizzled
__global__ __launch_bounds__(256) void out_gemm_kernel(
    const unsigned short* __restrict__ A, const unsigned short* __restrict__ Bt,
    const float* __restrict__ bias, float* __restrict__ C)
{
  __shared__ __align__(16) char lds[49152];
  const int id = blockIdx.x;
  gemm_body(A, Bt, bias, C, 1024, 1024, id & 7, id >> 3, 0, 1.f, lds);
}

// --------------------- MFMA flash attention (bf16, fp32 acc) -----------------
// Q [B*LQ, H] (pre-scaled by log2e/8), K [B*LK, H], Vt [B*H, LK], O [B*LQ, H].
// 128 q-rows/block, 4 waves x 32 q-rows; kc-tile = 64.
// TRIPLE-buffered K/V with counted vmcnt (same discipline as gemm_body):
// `s_waitcnt vmcnt(4); s_barrier` leaves the next tile's 4 g2l in flight.
// QK^T SWAPPED (mfma(K,Q) = S^T): lane holds 4 consecutive kc of one q-row ->
// P packs into 8 ds_write_b64/iter.
// P layout: 128 rows x 128B, XOR-swizzled byte ^= ((5*row)&7)<<4. Read phases
// (8 consecutive lanes) then hit 8 DISTINCT bank-quads (quad = lg ^ (5*l15&7),
// bijective per phase) -> conflict-free b128 reads; b64 writes <=2-way (free).
__global__ __launch_bounds__(256) void attn_mfma_kernel(
    const unsigned short* __restrict__ Q, const unsigned short* __restrict__ K,
    const unsigned short* __restrict__ Vt, unsigned short* __restrict__ O)
{
  // slot s at s*16384: K tile [0,8K) + V tile [8K,16K). P at 49152 (128 x 128B)
  __shared__ __align__(16) char lds[65536];
  constexpr int POFF = 49152;
  const int t    = threadIdx.x;
  const int lane = t & 63;
  const int w    = t >> 6;
  const int l15  = lane & 15;
  const int lg   = lane >> 4;
  const int lq8  = lg * 8;
  const int lq4  = lg * 4;
  const int flat = blockIdx.x;
  const int bh   = flat & 63;
  const int qb   = flat >> 6;
  const int h    = bh & 15;
  const int b    = bh >> 4;
  const int q0   = qb * 128;
  const int hoff = h * kHD;
  constexpr int NT = kLK / 64;   // 32 kc-tiles

  bf16x8 qf[2][2];
#pragma unroll
  for (int qi = 0; qi < 2; ++qi)
#pragma unroll
    for (int kh = 0; kh < 2; ++kh)
      qf[qi][kh] = *(const bf16x8*)(Q + (size_t)(b*kLQ + q0 + w*32 + qi*16 + l15) * kH
                                      + hoff + kh*32 + lq8);

  f32x4 acc[2][4] = {};
  float lsum[2] = {0.f, 0.f};

  // P swizzle: row-local XOR of bits 4-6 by ((5*row)&7); row&7 == l15&7.
  const int swz  = ((l15 * 5) & 7) << 4;
  const int colw = (lg * 8)  ^ swz;   // write column base (b64)
  const int colr = (lg * 16) ^ swz;   // read column base (b128)

  // per-thread staging addresses (4 g2l per kc-tile)
  const unsigned short* gsrc[4];
  int gstep[4];
  char* ldst[4];
#pragma unroll
  for (int i = 0; i < 4; ++i) {
    const int g = w * 4 + i;
    if (g < 8) {
      gsrc[i]  = K + (size_t)(b*kLK + (g >> 1)*16 + l15) * kH + hoff + (g & 1)*32 + lq8;
      gstep[i] = 64 * kH;                       // advance 64 kc rows
    } else {
      const int gg = g - 8;
      gsrc[i]  = Vt + (size_t)(b*kH + hoff + (gg >> 1)*16 + l15) * kLK + (gg & 1)*32 + lq8;
      gstep[i] = 64;                            // advance 64 kc cols
    }
    ldst[i] = lds + g * 1024 + lane * 16;       // g>=8 lands at 8192+gg*1024
  }

  // prologue: tile 0 -> slot 0, tile 1 -> slot 1
#pragma unroll
  for (int i = 0; i < 4; ++i) g2l16(gsrc[i], ldst[i]);
#pragma unroll
  for (int i = 0; i < 4; ++i) g2l16(gsrc[i] + gstep[i], ldst[i] + 16384);

  int slot = 0;
  for (int kt = 0; kt < NT; ++kt) {
    if (kt + 1 < NT) {
      asm volatile("s_waitcnt vmcnt(4)\n\ts_barrier" ::: "memory");
    } else {
      asm volatile("s_waitcnt vmcnt(0)\n\ts_barrier" ::: "memory");
    }
    char* buf = lds + slot * 16384;
    if (kt + 2 < NT) {
      int ns = slot + 2; if (ns >= 3) ns -= 3;
#pragma unroll
      for (int i = 0; i < 4; ++i)
        g2l16(gsrc[i] + (size_t)(kt + 2) * gstep[i], ldst[i] + ns * 16384);
    }

    // S^T = K Q^T : lane holds S[kc = kcf*16+lq4+r][q = w*32+qi*16+l15]
    f32x4 s[2][4];
#pragma unroll
    for (int kcf = 0; kcf < 4; ++kcf) {
      const bf16x8 kf0 = *(const bf16x8*)(buf + (kcf*2 + 0) * 1024 + lane * 16);
      const bf16x8 kf1 = *(const bf16x8*)(buf + (kcf*2 + 1) * 1024 + lane * 16);
#pragma unroll
      for (int qi = 0; qi < 2; ++qi) {
        f32x4 z = {};
        z = __builtin_amdgcn_mfma_f32_16x16x32_bf16(kf0, qf[qi][0], z, 0, 0, 0);
        z = __builtin_amdgcn_mfma_f32_16x16x32_bf16(kf1, qf[qi][1], z, 0, 0, 0);
        s[qi][kcf] = z;
      }
    }

    // P = exp2(s) (Q pre-scaled); pack 4 kc -> one b64 store per (qi,kcf).
#pragma unroll
    for (int qi = 0; qi < 2; ++qi) {
      char* const prow = lds + POFF + (w*32 + qi*16 + l15) * 128;
#pragma unroll
      for (int kcf = 0; kcf < 4; ++kcf) {
        const float p0 = __builtin_amdgcn_exp2f(s[qi][kcf][0]);
        const float p1 = __builtin_amdgcn_exp2f(s[qi][kcf][1]);
        const float p2 = __builtin_amdgcn_exp2f(s[qi][kcf][2]);
        const float p3 = __builtin_amdgcn_exp2f(s[qi][kcf][3]);
        lsum[qi] += (p0 + p1) + (p2 + p3);
        u32x2 pw;
        pw.x = __builtin_amdgcn_perm(__float_as_uint(p1), __float_as_uint(p0), 0x07060302u);
        pw.y = __builtin_amdgcn_perm(__float_as_uint(p3), __float_as_uint(p2), 0x07060302u);
        *(u32x2*)(prow + (colw ^ (kcf * 32))) = pw;
      }
    }

    // O += P V (P rows per-wave-private; no barrier needed)
    bf16x8 pf[2][2];
#pragma unroll
    for (int qi = 0; qi < 2; ++qi) {
      const char* const prow = lds + POFF + (w*32 + qi*16 + l15) * 128;
#pragma unroll
      for (int kq = 0; kq < 2; ++kq)
        pf[qi][kq] = *(const bf16x8*)(prow + (colr ^ (kq * 64)));
    }
#pragma unroll
    for (int vd = 0; vd < 4; ++vd) {
      const bf16x8 vf0 = *(const bf16x8*)(buf + 8192 + (vd*2 + 0) * 1024 + lane * 16);
      const bf16x8 vf1 = *(const bf16x8*)(buf + 8192 + (vd*2 + 1) * 1024 + lane * 16);
#pragma unroll
      for (int qi = 0; qi < 2; ++qi) {
        acc[qi][vd] = __builtin_amdgcn_mfma_f32_16x16x32_bf16(pf[qi][0], vf0, acc[qi][vd], 0, 0, 0);
        acc[qi][vd] = __builtin_amdgcn_mfma_f32_16x16x32_bf16(pf[qi][1], vf1, acc[qi][vd], 0, 0, 0);
      }
    }
    slot = (slot == 2) ? 0 : slot + 1;
  }

  // row sums: lane holds partial for q = l15 over its kc slice; reduce across
  // the 4 lane-groups, then redistribute 1/sum to acc row owners (q = lq4+r).
  float rinv[2][4];
#pragma unroll
  for (int qi = 0; qi < 2; ++qi) {
    float v = lsum[qi];
    v += __shfl_xor(v, 16);
    v += __shfl_xor(v, 32);
    v = 1.f / v;
#pragma unroll
    for (int r = 0; r < 4; ++r) rinv[qi][r] = __shfl(v, lq4 + r);
  }
#pragma unroll
  for (int qi = 0; qi < 2; ++qi)
#pragma unroll
    for (int vd = 0; vd < 4; ++vd)
#pragma unroll
      for (int r = 0; r < 4; ++r)
        O[(size_t)(b*kLQ + q0 + w*32 + qi*16 + lq4 + r) * kH + hoff + vd*16 + l15] =
            f2bf(acc[qi][vd][r] * rinv[qi][r]);
}

extern "C" void kernel_launch(void* const* d_in, const int* in_sizes, int n_in,
                              void* d_out, int out_size, void* d_ws, size_t ws_size,
                              hipStream_t stream) {
  (void)in_sizes; (void)n_in; (void)out_size; (void)ws_size;
  const float* query = (const float*)d_in[0];
  const float* key   = (const float*)d_in[1];
  const float* value = (const float*)d_in[2];
  const float* Wq = (const float*)d_in[3];
  const float* bq = (const float*)d_in[4];
  const float* Wk = (const float*)d_in[5];
  const float* bk = (const float*)d_in[6];
  const float* Wv = (const float*)d_in[7];
  const float* bv = (const float*)d_in[8];
  const float* Wo = (const float*)d_in[9];
  const float* bo = (const float*)d_in[10];
  float* out = (float*)d_out;

  unsigned short* ws  = (unsigned short*)d_ws;
  unsigned short* qA  = ws;                  // 4*1024*768
  unsigned short* kA  = qA  + 3145728;       // 4*2048*512
  unsigned short* vA  = kA  + 4194304;
  unsigned short* WqT = vA  + 4194304;       // 1024*768
  unsigned short* WkT = WqT + 786432;        // 1024*512
  unsigned short* WvT = WkT + 524288;
  unsigned short* WoT = WvT + 524288;        // 1024*1024
  unsigned short* Qb  = WoT + 1048576;       // 4096*1024
  unsigned short* Kb  = Qb  + 4194304;       // 8192*1024
  unsigned short* Vtw = Kb  + 8388608;       // 4096*2048 (transposed V)
  unsigned short* Ab  = Vtw + 8388608;       // 4096*1024

  prep_kernel<<<6336, 256, 0, stream>>>(query, key, value, Wq, Wk, Wv, Wo,
                                        qA, kA, vA, WqT, WkT, WvT, WoT);
  qkv_gemm_kernel<<<1280, 256, 0, stream>>>(qA, WqT, bq, Qb,
                                            kA, WkT, bk, Kb,
                                            vA, WvT, bv, Vtw);
  attn_mfma_kernel<<<512, 256, 0, stream>>>(Qb, Kb, Vtw, Ab);
  out_gemm_kernel<<<256, 256, 0, stream>>>(Ab, WoT, bo, out);
}